// Round 6
// baseline (762.271 us; speedup 1.0000x reference)
//
#include <hip/hip_runtime.h>

typedef __bf16 bf16;
typedef __bf16 bf16x8 __attribute__((ext_vector_type(8)));
typedef __bf16 bf16x4 __attribute__((ext_vector_type(4)));
typedef float  f32x4  __attribute__((ext_vector_type(4)));

#define GLOAD_LDS(gp, lp) \
    __builtin_amdgcn_global_load_lds( \
        (const __attribute__((address_space(1))) void*)(gp), \
        (__attribute__((address_space(3))) void*)(lp), 16, 0, 0)

// ---------------------------------------------------------------------------
// f32 -> bf16 convert, 4-wide
// ---------------------------------------------------------------------------
__global__ void f2b_kernel(const float* __restrict__ src, bf16* __restrict__ dst, int n4) {
    int i = blockIdx.x * 256 + threadIdx.x;
    if (i >= n4) return;
    float4 v = ((const float4*)src)[i];
    bf16x4 o = { (bf16)v.x, (bf16)v.y, (bf16)v.z, (bf16)v.w };
    ((bf16x4*)dst)[i] = o;
}

// ---------------------------------------------------------------------------
// zero the appended row n of the activation buffers (gather zero-row trick)
// ---------------------------------------------------------------------------
__global__ void zrow_kernel(bf16* F3, bf16* F2, bf16* tA, bf16* tB, bf16* z, int n) {
    int t = threadIdx.x;
    if (t < 96)  F3[(size_t)n * 96  + t] = (bf16)0.f;
    if (t < 256) F2[(size_t)n * 256 + t] = (bf16)0.f;
    if (t < 64)  tA[(size_t)n * 64  + t] = (bf16)0.f;
    if (t < 64)  tB[(size_t)n * 64  + t] = (bf16)0.f;
    if (t < 96)  z [(size_t)n * 96  + t] = (bf16)0.f;
}

// ---------------------------------------------------------------------------
// Swizzle fp32 W (taps, cin, cout) into bf16 MFMA-B-fragment order:
//   Wf[tap][s][nt][lane][j] = W[tap][s*32 + (lane>>4)*8 + j][nt*16 + (lane&15)]
// ---------------------------------------------------------------------------
__global__ void swz_kernel(const float* __restrict__ W, bf16* __restrict__ Wf,
                           int cin, int cout, int total) {
    int e = blockIdx.x * 256 + threadIdx.x;
    if (e >= total) return;
    int per_tap = cin * cout;
    int tap = e / per_tap;
    int t2  = e - tap * per_tap;
    int ntc = cout >> 4;
    int s   = t2 / (ntc * 512);
    int r3  = t2 - s * (ntc * 512);
    int nt  = r3 >> 9;
    int L   = (r3 & 511) >> 3;
    int j   = r3 & 7;
    int k   = s * 32 + (L >> 4) * 8 + j;
    int col = nt * 16 + (L & 15);
    Wf[e] = (bf16)W[((size_t)tap * cin + k) * cout + col];
}

// ---------------------------------------------------------------------------
// Fused chain: h1 = relu(bn(sconv(X,W1))); h2 = relu(bn(h1@W2));
//              optional h3 = relu(bn(h2@W3)).
// Sparse stage: 128-row blocks, 4 waves. Each wave owns 64 rows exclusively
// (WR=4 row-tiles). SPLITK=1: wave pairs split the tap range, fp32 partial
// accs exchanged through LDS at the end. SPLITK=0 (C1=128): wave pairs split
// output columns instead. K-loop is BARRIER-FREE: A gathered via
// global_load_lds (per-lane addresses, invalid -> zero row n) into the
// wave's PRIVATE double-buffered LDS slab; pacing via s_waitcnt vmcnt(N).
// B-fragments global->VGPR, double-buffered. Dense stages: LDS tile handoff.
// ---------------------------------------------------------------------------
template<int CIN, int C1, int TAPS, int C2, int C3, int SPLITK>
__global__ __launch_bounds__(256) void layer_kernel(
    const bf16* __restrict__ X,
    const bf16* __restrict__ W1, const bf16* __restrict__ W2,
    const bf16* __restrict__ W3,
    const int* __restrict__ nbr,
    const float* __restrict__ sc1, const float* __restrict__ sh1,
    const float* __restrict__ sc2, const float* __restrict__ sh2,
    const float* __restrict__ sc3, const float* __restrict__ sh3,
    bf16* __restrict__ Y, float* __restrict__ Yf,
    int ystride, int n)
{
    constexpr int KH    = CIN / 32;         // K-steps of 32 per tap
    constexpr int NT1   = C1 / 16;
    constexpr int WC    = SPLITK ? NT1 : NT1 / 2;   // col-tiles per wave
    constexpr int WR    = 4;                // 64 rows per wave
    constexpr int HC    = WC / 2;
    constexpr int SLABB = 4096;             // 64 rows x 32k x 2B
    constexpr int IDXB  = TAPS * 128 * 4;
    constexpr int TSPLIT = (TAPS + 1) / 2;
    constexpr int ILAST = TAPS * KH - 1;
    constexpr int NB    = WC;               // B loads per iter
    constexpr int LS1   = C1 + 8;
    constexpr int LS2   = C2 + 8;
    constexpr int SMEMB = IDXB + 8 * SLABB; // 46592 for TAPS=27
    static_assert(128 * LS1 * 2 <= SMEMB, "tile1");
    static_assert(C3 == 0 || 128 * LS2 * 2 <= SMEMB, "tile2");

    __shared__ __align__(16) char smem[SMEMB];

    const int tid  = threadIdx.x, lane = tid & 63, wv = tid >> 6;
    const int m16  = lane & 15, quad = lane >> 4;
    const int rh   = wv & 1;                // row half
    const int g    = wv >> 1;               // tap half (SPLITK) / col group
    const int base = blockIdx.x * 128;

    // ---- neighbor byte-offsets (invalid -> zero row n) ----
    int* idxs = (int*)smem;
    for (int e = tid; e < TAPS * 128; e += 256) {
        int t = e >> 7, rr = e & 127;
        int idx = nbr[t * n + base + rr];
        idxs[e] = (idx < 0 ? n : idx) * (CIN * 2);
    }
    __syncthreads();

    const int i0   = (SPLITK && g) ? TSPLIT * KH : 0;
    const int NIT  = SPLITK ? ((g ? TAPS - TSPLIT : TSPLIT) * KH) : TAPS * KH;
    const int cb   = SPLITK ? 0 : g * WC;
    const int slab0 = IDXB + wv * 2 * SLABB;
    const char* Xb = (const char*)X;
    const int lrow = rh * 64 + lane;        // this lane's staged row (in block)

    f32x4 acc[WR][WC];
#pragma unroll
    for (int j = 0; j < WR; ++j)
#pragma unroll
        for (int c = 0; c < WC; ++c) acc[j][c] = (f32x4){0.f, 0.f, 0.f, 0.f};

    bf16x8 Bb[2][WC];

    auto stageA = [&](int ig, int sb) {
        int t = ig / KH, kh = ig - t * KH;
        int voff = idxs[t * 128 + lrow];
        const char* gp = Xb + voff + kh * 64;
        char* lp = smem + sb;
#pragma unroll
        for (int kc = 0; kc < 4; ++kc)
            GLOAD_LDS(gp + kc * 16, lp + kc * 1024);
    };
    auto loadB = [&](int ig, int which) {
        const bf16* p = W1 + ((size_t)ig * NT1 + cb) * 512 + lane * 8;
#pragma unroll
        for (int c = 0; c < WC; ++c)
            Bb[which][c] = *(const bf16x8*)(p + c * 512);
    };
    auto compute = [&](int sb, int which) {
        bf16x8 a[WR];
#pragma unroll
        for (int j = 0; j < WR; ++j)
            a[j] = *(const bf16x8*)(smem + sb + quad * 1024 + (j * 16 + m16) * 16);
#pragma unroll
        for (int j = 0; j < WR; ++j)
#pragma unroll
            for (int c = 0; c < WC; ++c)
                acc[j][c] = __builtin_amdgcn_mfma_f32_16x16x32_bf16(a[j], Bb[which][c], acc[j][c], 0, 0, 0);
    };

    // ---- barrier-free pipelined sparse loop (lookahead-1) ----
    stageA(i0, slab0);
    loadB(i0, 0);
    for (int iw = 0; iw < NIT; iw += 2) {
        {
            int ign = i0 + iw + 1; if (ign > ILAST) ign = ILAST;
            loadB(ign, 1);
            stageA(ign, slab0 + SLABB);
            asm volatile("s_waitcnt vmcnt(%0)" :: "i"(NB + 4) : "memory");
            compute(slab0, 0);
        }
        if (iw + 1 < NIT) {
            int ign = i0 + iw + 2; if (ign > ILAST) ign = ILAST;
            loadB(ign, 0);
            stageA(ign, slab0);
            asm volatile("s_waitcnt vmcnt(%0)" :: "i"(NB + 4) : "memory");
            compute(slab0 + SLABB, 1);
        }
    }
    asm volatile("s_waitcnt vmcnt(0)" ::: "memory");   // drain tail DMAs

    // ---- SPLITK: exchange partial accumulators through own slab ----
    if constexpr (SPLITK) {
        float* D = (float*)(smem + slab0);
#pragma unroll
        for (int cc = 0; cc < HC; ++cc) {
            int c = (1 - g) * HC + cc;                 // dump the half we give away
#pragma unroll
            for (int j = 0; j < WR; ++j)
#pragma unroll
                for (int i = 0; i < 4; ++i)
                    D[((cc * WR + j) * 4 + i) * 64 + lane] = acc[j][c][i];
        }
        __syncthreads();
        const float* P = (const float*)(smem + IDXB + (wv ^ 2) * 2 * SLABB);
#pragma unroll
        for (int cc = 0; cc < HC; ++cc) {
            int c = g * HC + cc;                       // our kept half
#pragma unroll
            for (int j = 0; j < WR; ++j)
#pragma unroll
                for (int i = 0; i < 4; ++i)
                    acc[j][c][i] += P[((cc * WR + j) * 4 + i) * 64 + lane];
        }
        __syncthreads();
    } else {
        __syncthreads();
    }

    // ---- stage-1 epilogue -> tile1 (aliases idxs + slabs; all dead now) ----
    bf16* T1 = (bf16*)smem;
    {
        constexpr int CN = SPLITK ? HC : WC;
#pragma unroll
        for (int cc = 0; cc < CN; ++cc) {
            int ci  = SPLITK ? (g * HC + cc) : cc;     // acc index
            int ct  = SPLITK ? (g * HC + cc) : (cb + cc);  // absolute col tile
            int col = ct * 16 + m16;
            float s1 = sc1[col], h1 = sh1[col];
#pragma unroll
            for (int j = 0; j < WR; ++j) {
                int row0 = rh * 64 + j * 16 + quad * 4;
#pragma unroll
                for (int i = 0; i < 4; ++i) {
                    float v = acc[j][ci][i] * s1 + h1;
                    v = v > 0.f ? v : 0.f;
                    T1[(row0 + i) * LS1 + col] = (bf16)v;
                }
            }
        }
    }
    __syncthreads();

    // ---- stage 2: dense GEMM, rows wv*32.., full C2 ----
    constexpr int NT2 = C2 / 16, KS2 = C1 / 32;
    f32x4 acc2[2][NT2];
#pragma unroll
    for (int j = 0; j < 2; ++j)
#pragma unroll
        for (int c = 0; c < NT2; ++c) acc2[j][c] = (f32x4){0.f, 0.f, 0.f, 0.f};
#pragma unroll
    for (int s = 0; s < KS2; ++s) {
        bf16x8 a[2], bw[NT2];
#pragma unroll
        for (int j = 0; j < 2; ++j)
            a[j] = *(const bf16x8*)(&T1[(wv * 32 + j * 16 + m16) * LS1 + s * 32 + quad * 8]);
#pragma unroll
        for (int c = 0; c < NT2; ++c)
            bw[c] = *(const bf16x8*)(W2 + ((size_t)(s * NT2 + c)) * 512 + lane * 8);
#pragma unroll
        for (int j = 0; j < 2; ++j)
#pragma unroll
            for (int c = 0; c < NT2; ++c)
                acc2[j][c] = __builtin_amdgcn_mfma_f32_16x16x32_bf16(a[j], bw[c], acc2[j][c], 0, 0, 0);
    }

    if constexpr (C3 == 0) {
        // ---- final epilogue (bf16) ----
#pragma unroll
        for (int c = 0; c < NT2; ++c) {
            int col = c * 16 + m16;
            float s2 = sc2[col], h2 = sh2[col];
#pragma unroll
            for (int j = 0; j < 2; ++j) {
                int row0 = base + wv * 32 + j * 16 + quad * 4;
#pragma unroll
                for (int i = 0; i < 4; ++i) {
                    float v = acc2[j][c][i] * s2 + h2;
                    v = v > 0.f ? v : 0.f;
                    Y[(size_t)(row0 + i) * ystride + col] = (bf16)v;
                }
            }
        }
    } else {
        __syncthreads();                               // tile1 reads done
        bf16* T2 = (bf16*)smem;                        // aliases tile1
#pragma unroll
        for (int c = 0; c < NT2; ++c) {
            int col = c * 16 + m16;
            float s2 = sc2[col], h2 = sh2[col];
#pragma unroll
            for (int j = 0; j < 2; ++j) {
                int row0 = wv * 32 + j * 16 + quad * 4;
#pragma unroll
                for (int i = 0; i < 4; ++i) {
                    float v = acc2[j][c][i] * s2 + h2;
                    v = v > 0.f ? v : 0.f;
                    T2[(row0 + i) * LS2 + col] = (bf16)v;
                }
            }
        }
        __syncthreads();

        constexpr int C3v = (C3 > 0) ? C3 : 16;
        constexpr int NT3 = C3v / 16, KS3 = C2 / 32;
        f32x4 acc3[2][NT3];
#pragma unroll
        for (int j = 0; j < 2; ++j)
#pragma unroll
            for (int c = 0; c < NT3; ++c) acc3[j][c] = (f32x4){0.f, 0.f, 0.f, 0.f};
#pragma unroll
        for (int s = 0; s < KS3; ++s) {
            bf16x8 a[2], bw[NT3];
#pragma unroll
            for (int j = 0; j < 2; ++j)
                a[j] = *(const bf16x8*)(&T2[(wv * 32 + j * 16 + m16) * LS2 + s * 32 + quad * 8]);
#pragma unroll
            for (int c = 0; c < NT3; ++c)
                bw[c] = *(const bf16x8*)(W3 + ((size_t)(s * NT3 + c)) * 512 + lane * 8);
#pragma unroll
            for (int j = 0; j < 2; ++j)
#pragma unroll
                for (int c = 0; c < NT3; ++c)
                    acc3[j][c] = __builtin_amdgcn_mfma_f32_16x16x32_bf16(a[j], bw[c], acc3[j][c], 0, 0, 0);
        }
#pragma unroll
        for (int c = 0; c < NT3; ++c) {
            int col = c * 16 + m16;
            float s3 = sc3[col], h3 = sh3[col];
#pragma unroll
            for (int j = 0; j < 2; ++j) {
                int row0 = base + wv * 32 + j * 16 + quad * 4;
#pragma unroll
                for (int i = 0; i < 4; ++i) {
                    float v = acc3[j][c][i] * s3 + h3;
                    v = v > 0.f ? v : 0.f;
                    Yf[(size_t)(row0 + i) * ystride + col] = v;
                }
            }
        }
    }
}

// ---------------------------------------------------------------------------
// z[:, 64:96] = sanitize(y2[align_idx])
// ---------------------------------------------------------------------------
__global__ void concat_kernel(const bf16* __restrict__ y2, const int* __restrict__ align,
                              bf16* __restrict__ z, int n) {
    int e = blockIdx.x * 256 + threadIdx.x;
    if (e >= n * 32) return;
    int i = e >> 5, c = e & 31;
    int a = align[i];
    float v = (float)y2[(size_t)a * 32 + c];
    unsigned u = __builtin_bit_cast(unsigned, v);
    if ((u & 0x7f800000u) == 0x7f800000u) v = 0.f;
    z[(size_t)i * 96 + 64 + c] = (bf16)v;
}

// ---------------------------------------------------------------------------
extern "C" void kernel_launch(void* const* d_in, const int* in_sizes, int n_in,
                              void* d_out, int out_size, void* d_ws, size_t ws_size,
                              hipStream_t stream) {
    const float* feat3d = (const float*)d_in[0];
    const float* feat2d = (const float*)d_in[1];
    const float* Wsrc[11];
    for (int i = 0; i < 11; ++i) Wsrc[i] = (const float*)d_in[2 + i];
    const float* bn[22];
    for (int i = 0; i < 22; ++i) bn[i] = (const float*)d_in[13 + i];
    const int* nbr   = (const int*)d_in[35];
    const int* align = (const int*)d_in[36];
    float* out = (float*)d_out;

    const int n = in_sizes[0] / 96;   // 80000 (divisible by 128)

    char* ws = (char*)d_ws;
    size_t off = 0;
    auto alloc = [&](size_t bytes) -> void* {
        void* p = ws + off;
        off = (off + bytes + 255) & ~(size_t)255;
        return p;
    };
    bf16* F3 = (bf16*)alloc((size_t)(n + 1) * 96 * 2);
    bf16* F2 = (bf16*)alloc((size_t)(n + 1) * 256 * 2);
    static const int wt_taps[11] = {27, 1, 27, 1, 27, 1, 27, 1, 27, 1, 1};
    static const int wt_cin[11]  = {96, 64, 64, 64, 256, 64, 64, 32, 96, 128, 128};
    static const int wt_cout[11] = {64, 64, 64, 64, 64, 64, 32, 32, 128, 128, 128};
    bf16* Wf[11];
    for (int i = 0; i < 11; ++i)
        Wf[i] = (bf16*)alloc((size_t)wt_taps[i] * wt_cin[i] * wt_cout[i] * 2);
    bf16* tA = (bf16*)alloc((size_t)(n + 1) * 64 * 2);
    bf16* tB = (bf16*)alloc((size_t)(n + 1) * 64 * 2);
    bf16* y2 = (bf16*)alloc((size_t)n * 32 * 2);
    bf16* z  = (bf16*)alloc((size_t)(n + 1) * 96 * 2);

    // ---- prep ----
    f2b_kernel<<<(n * 96 / 4 + 255) / 256, 256, 0, stream>>>(feat3d, F3, n * 96 / 4);
    f2b_kernel<<<(n * 256 / 4 + 255) / 256, 256, 0, stream>>>(feat2d, F2, n * 256 / 4);
    zrow_kernel<<<1, 256, 0, stream>>>(F3, F2, tA, tB, z, n);
    for (int i = 0; i < 11; ++i) {
        int total = wt_taps[i] * wt_cin[i] * wt_cout[i];
        swz_kernel<<<(total + 255) / 256, 256, 0, stream>>>(Wsrc[i], Wf[i], wt_cin[i], wt_cout[i], total);
    }

    const int GB = n / 128;   // 625 blocks

    // ---- 3D branch: (a1+a2), (a3+a4) ----
    layer_kernel<96, 64, 27, 64, 0, 1><<<GB, 256, 0, stream>>>(
        F3, Wf[0], Wf[1], nullptr, nbr,
        bn[0], bn[1], bn[2], bn[3], nullptr, nullptr,
        tB, nullptr, 64, n);
    layer_kernel<64, 64, 27, 64, 0, 1><<<GB, 256, 0, stream>>>(
        tB, Wf[2], Wf[3], nullptr, nbr,
        bn[4], bn[5], bn[6], bn[7], nullptr, nullptr,
        z, nullptr, 96, n);                        // x3 -> z[:,0:64]

    // ---- 2D branch: (b1+b2), (b3+b4) ----
    layer_kernel<256, 64, 27, 64, 0, 1><<<GB, 256, 0, stream>>>(
        F2, Wf[4], Wf[5], nullptr, nbr,
        bn[8], bn[9], bn[10], bn[11], nullptr, nullptr,
        tA, nullptr, 64, n);
    layer_kernel<64, 32, 27, 32, 0, 1><<<GB, 256, 0, stream>>>(
        tA, Wf[6], Wf[7], nullptr, nbr,
        bn[12], bn[13], bn[14], bn[15], nullptr, nullptr,
        y2, nullptr, 32, n);

    concat_kernel<<<(n * 32 + 255) / 256, 256, 0, stream>>>(y2, align, z, n);

    // ---- fusion: (c1+c2+c3), col-split waves ----
    layer_kernel<96, 128, 27, 128, 128, 0><<<GB, 256, 0, stream>>>(
        z, Wf[8], Wf[9], Wf[10], nbr,
        bn[16], bn[17], bn[18], bn[19], bn[20], bn[21],
        nullptr, out, 128, n);
}